// Round 3
// baseline (290.289 us; speedup 1.0000x reference)
//
#include <hip/hip_runtime.h>
#include <stdint.h>

// CrossNetwork fused: x:[16384,512] f32, W:[4,512,512] f32, b:[4,512] f32
// out:[16384,2048] f32 = concat(x1..x4).
//
// Algebra: residual loop collapses to x_eff = x_l + c_l*1 with
//   c = 0; for j<l: c = c + dot(x_l,x_j) + c*sum(x_j)
// and (x_l + c*1)@W^T = x_l@W^T + c*rowsum(W).
//
// R5: ROW-WISE INDEPENDENCE -> one persistent block owns BM=64 rows and runs
// ALL 4 layers locally. Activations never leave the die:
//  - act: 64KB XOR-swizzled LDS, holds current layer's A-operand; epilogue l
//    writes x_{l+1} in place (each element touched by exactly one thread).
//  - x0/x1/x2 dot-operands: packed bf16 in per-thread registers at the
//    thread's fixed C-layout positions (vk0/vk1/vk2) -> dots are register FMAs
//    + 16-lane shfl reduce + tiny LDS fold. No global partials, no global sync.
//  - B (Wb[l], 2MB total) stays L2-resident; staged per K-step via
//    global_load_lds with PRE-SWIZZLED SOURCE (linear LDS dest, rule #21),
//    read with the same chunk-XOR -> 4-way instead of 8-way bank conflict.
//  - K-loop: 2-buffer, counted vmcnt(4) (never 0 in steady state), 2 raw
//    barriers/step; staging indexes a GLOBAL step s=0..63 so prefetch runs
//    across layer boundaries.
// Grid: 256 blocks (exactly 1/CU, no tail) x 512 threads. 2 dispatches total.

#define BROWS 16384
#define DIM 512
#define NL 4
#define OUTSTRIDE (NL * DIM)

#define BM 64
#define BK 32
#define SEG (DIM / BK)        // 16 K-steps per layer
#define NSTEP (NL * SEG)      // 64 global K-steps

typedef unsigned short ushort_t;
typedef __attribute__((ext_vector_type(8))) short bf16x8;
typedef __attribute__((ext_vector_type(4))) float f32x4;

__device__ inline ushort_t f32_to_bf16(float f) {
    union { float f; uint32_t u; } v; v.f = f;
    uint32_t u = v.u;
    uint32_t r = (u + 0x7fffu + ((u >> 16) & 1u)) >> 16;   // RNE
    return (ushort_t)r;
}

__device__ inline float bf16_lo(uint32_t p) {   // low bf16 of packed pair
    union { uint32_t u; float f; } v; v.u = p << 16; return v.f;
}
__device__ inline float bf16_hi(uint32_t p) {   // high bf16 of packed pair
    union { uint32_t u; float f; } v; v.u = p & 0xffff0000u; return v.f;
}

__device__ inline float wave_reduce_sum(float v) {
    #pragma unroll
    for (int off = 32; off > 0; off >>= 1) v += __shfl_down(v, off, 64);
    return v;
}

// ---------------------------------------------------------------------------
// prep: W f32 -> bf16 + wsum[l][e] = sum_d W[l][e][d]. 2048 blocks x 256.
// ---------------------------------------------------------------------------
__global__ __launch_bounds__(256) void prep_kernel(
    const float* __restrict__ W, ushort_t* __restrict__ Wb,
    float* __restrict__ wsum)
{
    int row = blockIdx.x;      // l*512 + e
    int t = threadIdx.x;
    const float* wp = W + (size_t)row * DIM;
    float f0 = wp[2 * t], f1 = wp[2 * t + 1];
    ushort_t* wbp = Wb + (size_t)row * DIM;
    wbp[2 * t]     = f32_to_bf16(f0);
    wbp[2 * t + 1] = f32_to_bf16(f1);
    __shared__ float red[4];
    int wave = t >> 6, lane = t & 63;
    float r = wave_reduce_sum(f0 + f1);
    if (lane == 0) red[wave] = r;
    __syncthreads();
    if (t == 0) wsum[row] = red[0] + red[1] + red[2] + red[3];
}

// ---------------------------------------------------------------------------
// fused main kernel
// ---------------------------------------------------------------------------
__global__ __launch_bounds__(512, 1) void cross_kernel(
    const float* __restrict__ x0,
    const ushort_t* __restrict__ Wb,    // [4][512][512] bf16 bits
    const float* __restrict__ bias,     // [4][512]
    const float* __restrict__ wsum,     // [4][512]
    float* __restrict__ out)            // [16384][2048]
{
    // act: [64 rows][512 cols] bf16, chunk-swizzled: 16B-chunk kc at
    //   elem = row*512 + ((kc ^ (row&7))<<3) + (col&7)
    __shared__ __align__(16) ushort_t sAct[BM * DIM];        // 64 KB
    __shared__ __align__(16) ushort_t sB[2][DIM * BK];       // 2 x 32 KB
    __shared__ float sRed[4][4][BM];                          // 4 KB
    __shared__ float sSums[4][BM];                            // 1 KB
    __shared__ float sCn[BM];

    int tid  = threadIdx.x;
    int wave = tid >> 6;
    int lane = tid & 63;
    int wm  = wave >> 2;       // 0..1: 32-row half
    int wn4 = wave & 3;        // 0..3: 128-col quarter
    int q = lane >> 4;         // 0..3
    int rr = lane & 15;
    int nlane = lane & 15;
    int bm = blockIdx.x * BM;

    // per-lane pre-swizzled B source offsets (elements), 4 chunk-calls/stage
    int beoff[4];
    #pragma unroll
    for (int j = 0; j < 4; ++j) {
        int brow = wave * 64 + j * 16 + (lane >> 2);   // W-row 0..511
        int chunk = (lane & 3) ^ (brow & 3);
        beoff[j] = brow * DIM + chunk * 8;
    }

    auto stageB = [&](int s) {    // global step s: layer s>>4, k0 = (s&15)*BK
        int cur = s & 1;
        const ushort_t* base = Wb + ((size_t)(s >> 4) * DIM + (size_t)((s & 15) * BK) / DIM) * DIM; // simplify below
        const ushort_t* gb = Wb + (size_t)(s >> 4) * DIM * DIM + (s & 15) * BK;
        (void)base;
        #pragma unroll
        for (int j = 0; j < 4; ++j) {
            __builtin_amdgcn_global_load_lds(
                (const __attribute__((address_space(1))) void*)(gb + beoff[j]),
                (__attribute__((address_space(3))) void*)(&sB[cur][(wave * 64 + j * 16) * BK]),
                16, 0, 0);
        }
    };

    stageB(0);
    stageB(1);

    // ---- x0 phase: stage rows into act (swizzled bf16) + sums[0] ----
    #pragma unroll
    for (int r8 = 0; r8 < 8; ++r8) {
        int row = wave * 8 + r8;
        const float* xp = x0 + (size_t)(bm + row) * DIM + lane * 8;
        float4 a = ((const float4*)xp)[0];
        float4 b4 = ((const float4*)xp)[1];
        float f[8] = {a.x, a.y, a.z, a.w, b4.x, b4.y, b4.z, b4.w};
        bf16x8 o;
        float s = 0.f;
        #pragma unroll
        for (int i = 0; i < 8; ++i) { o[i] = (short)f32_to_bf16(f[i]); s += f[i]; }
        int kc = lane ^ (row & 7);                 // logical chunk = lane
        *(bf16x8*)(&sAct[row * DIM + kc * 8]) = o;
        s = wave_reduce_sum(s);
        if (lane == 0) sSums[0][row] = s;
    }
    __syncthreads();

    // dot-operand register keeps (packed bf16 pairs at C-layout positions)
    uint32_t vk0[32], vk1[32], vk2[32];

    #pragma unroll
    for (int l = 0; l < NL; ++l) {
        f32x4 acc[2][8] = {};

        for (int t = 0; t < SEG; ++t) {
            int s = l * SEG + t;
            int cur = s & 1;
            // current tile ready; next stage's 4 loads stay in flight
            if (s < NSTEP - 1) { asm volatile("s_waitcnt vmcnt(4)" ::: "memory"); }
            else               { asm volatile("s_waitcnt vmcnt(0)" ::: "memory"); }
            __builtin_amdgcn_s_barrier();
            __builtin_amdgcn_sched_barrier(0);

            bf16x8 af[2], bfr[8];
            #pragma unroll
            for (int mi = 0; mi < 2; ++mi) {
                int arow = wm * 32 + mi * 16 + rr;
                int kc = (t * 4 + q) ^ (arow & 7);
                af[mi] = *(const bf16x8*)(&sAct[arow * DIM + kc * 8]);
            }
            int ch2 = q ^ (rr & 3);
            #pragma unroll
            for (int ni = 0; ni < 8; ++ni) {
                int erow = wn4 * 128 + ni * 16 + rr;
                bfr[ni] = *(const bf16x8*)(&sB[cur][erow * BK + ch2 * 8]);
            }
            asm volatile("s_waitcnt lgkmcnt(0)" ::: "memory");
            __builtin_amdgcn_sched_barrier(0);
            __builtin_amdgcn_s_barrier();
            if (s + 2 < NSTEP) stageB(s + 2);   // overwrites buf cur (reads done)

            #pragma unroll
            for (int mi = 0; mi < 2; ++mi)
                #pragma unroll
                for (int ni = 0; ni < 8; ++ni)
                    acc[mi][ni] = __builtin_amdgcn_mfma_f32_16x16x32_bf16(
                        af[mi], bfr[ni], acc[mi][ni], 0, 0, 0);
        }

        // ---------------- epilogue layer l ----------------
        float ws8[8], bs8[8];
        #pragma unroll
        for (int ni = 0; ni < 8; ++ni) {
            int ng = wn4 * 128 + ni * 16 + nlane;
            ws8[ni] = wsum[l * DIM + ng];
            bs8[ni] = bias[l * DIM + ng];
        }
        float cl8[8];
        #pragma unroll
        for (int mi = 0; mi < 2; ++mi)
            #pragma unroll
            for (int r = 0; r < 4; ++r)
                cl8[mi * 4 + r] = (l == 0) ? 0.f : sCn[wm * 32 + mi * 16 + q * 4 + r];

        if (l == 0) {
            // capture x0 at this thread's C-positions (before in-place x1 write)
            #pragma unroll
            for (int mi = 0; mi < 2; ++mi)
                #pragma unroll
                for (int r = 0; r < 4; ++r) {
                    int row = wm * 32 + mi * 16 + q * 4 + r;
                    #pragma unroll
                    for (int nip = 0; nip < 4; ++nip) {
                        int kc0 = (wn4 * 16 + 4 * nip + (nlane >> 3)) ^ (row & 7);
                        int kc1 = (wn4 * 16 + 4 * nip + 2 + (nlane >> 3)) ^ (row & 7);
                        uint32_t b0 = sAct[row * DIM + kc0 * 8 + (nlane & 7)];
                        uint32_t b1 = sAct[row * DIM + kc1 * 8 + (nlane & 7)];
                        vk0[(mi * 4 + r) * 4 + nip] = b0 | (b1 << 16);
                    }
                }
            asm volatile("s_waitcnt lgkmcnt(0)" ::: "memory");
        }

        #pragma unroll
        for (int mi = 0; mi < 2; ++mi)
            #pragma unroll
            for (int r = 0; r < 4; ++r) {
                int mr = mi * 4 + r;
                int row = wm * 32 + mi * 16 + q * 4 + r;
                float cc = cl8[mr];
                float vv[8];
                #pragma unroll
                for (int ni = 0; ni < 8; ++ni) {
                    vv[ni] = acc[mi][ni][r] + cc * ws8[ni] + bs8[ni];
                    int colg = wn4 * 128 + ni * 16 + nlane;
                    out[(size_t)(bm + row) * OUTSTRIDE + l * DIM + colg] = vv[ni];
                }
                if (l < 3) {
                    float vs = 0.f, d0 = 0.f, d1 = 0.f, d2 = 0.f;
                    #pragma unroll
                    for (int ni = 0; ni < 8; ++ni) vs += vv[ni];
                    #pragma unroll
                    for (int nip = 0; nip < 4; ++nip) {
                        uint32_t p0 = vk0[mr * 4 + nip];
                        d0 += vv[2 * nip] * bf16_lo(p0) + vv[2 * nip + 1] * bf16_hi(p0);
                        if (l >= 1) {
                            uint32_t p1 = vk1[mr * 4 + nip];
                            d1 += vv[2 * nip] * bf16_lo(p1) + vv[2 * nip + 1] * bf16_hi(p1);
                        }
                        if (l >= 2) {
                            uint32_t p2 = vk2[mr * 4 + nip];
                            d2 += vv[2 * nip] * bf16_lo(p2) + vv[2 * nip + 1] * bf16_hi(p2);
                        }
                    }
                    // in-place act write (x_{l+1}) + register keep
                    #pragma unroll
                    for (int nip = 0; nip < 4; ++nip) {
                        ushort_t h0 = f32_to_bf16(vv[2 * nip]);
                        ushort_t h1 = f32_to_bf16(vv[2 * nip + 1]);
                        int kc0 = (wn4 * 16 + 4 * nip + (nlane >> 3)) ^ (row & 7);
                        int kc1 = (wn4 * 16 + 4 * nip + 2 + (nlane >> 3)) ^ (row & 7);
                        sAct[row * DIM + kc0 * 8 + (nlane & 7)] = h0;
                        sAct[row * DIM + kc1 * 8 + (nlane & 7)] = h1;
                        uint32_t pk = (uint32_t)h0 | ((uint32_t)h1 << 16);
                        if (l == 0) vk1[mr * 4 + nip] = pk;
                        if (l == 1) vk2[mr * 4 + nip] = pk;
                    }
                    #pragma unroll
                    for (int off = 8; off > 0; off >>= 1) {
                        vs += __shfl_xor(vs, off, 64);
                        d0 += __shfl_xor(d0, off, 64);
                        if (l >= 1) d1 += __shfl_xor(d1, off, 64);
                        if (l >= 2) d2 += __shfl_xor(d2, off, 64);
                    }
                    if (nlane == 0) {
                        sRed[0][wn4][row] = vs;
                        sRed[1][wn4][row] = d0;
                        if (l >= 1) sRed[2][wn4][row] = d1;
                        if (l >= 2) sRed[3][wn4][row] = d2;
                    }
                }
            }

        if (l < 3) {
            __syncthreads();
            if (tid < BM) {
                float vs = sRed[0][0][tid] + sRed[0][1][tid] + sRed[0][2][tid] + sRed[0][3][tid];
                float d0 = sRed[1][0][tid] + sRed[1][1][tid] + sRed[1][2][tid] + sRed[1][3][tid];
                float c = d0;                                   // j=0: c = 0 + d0 + 0*s0
                if (l >= 1) {
                    float d1 = sRed[2][0][tid] + sRed[2][1][tid] + sRed[2][2][tid] + sRed[2][3][tid];
                    c = c + d1 + c * sSums[1][tid];
                }
                if (l >= 2) {
                    float d2 = sRed[3][0][tid] + sRed[3][1][tid] + sRed[3][2][tid] + sRed[3][3][tid];
                    c = c + d2 + c * sSums[2][tid];
                }
                sCn[tid] = c;
                sSums[l + 1][tid] = vs;
            }
            __syncthreads();
        }
    }
}

// ---------------------------------------------------------------------------
extern "C" void kernel_launch(void* const* d_in, const int* in_sizes, int n_in,
                              void* d_out, int out_size, void* d_ws, size_t ws_size,
                              hipStream_t stream) {
    (void)in_sizes; (void)n_in; (void)out_size; (void)ws_size;
    const float* x0   = (const float*)d_in[0];
    const float* W    = (const float*)d_in[1];
    const float* bias = (const float*)d_in[2];
    float* out = (float*)d_out;

    char* ws = (char*)d_ws;
    // workspace: Wb 4*512*512*2 = 2,097,152 @ 0; wsum 4*512*4 = 8,192 @ 2,097,152
    ushort_t* Wb   = (ushort_t*)ws;
    float*    wsum = (float*)(ws + 2097152);

    prep_kernel<<<NL * DIM, 256, 0, stream>>>(W, Wb, wsum);
    cross_kernel<<<BROWS / BM, 512, 0, stream>>>(x0, Wb, bias, wsum, out);
}

// Round 4
// 278.943 us; speedup vs baseline: 1.0407x; 1.0407x over previous
//
#include <hip/hip_runtime.h>
#include <stdint.h>

// CrossNetwork fused: x:[16384,512] f32, W:[4,512,512] f32, b:[4,512] f32
// out:[16384,2048] f32 = concat(x1..x4).
//
// Algebra: residual loop collapses to x_eff = x_l + c_l*1 with
//   c = 0; for j<l: c = c + dot(x_l,x_j) + c*sum(x_j)
// and (x_l + c*1)@W^T = x_l@W^T + c*rowsum(W).
//
// R6 (schedule fix over R5; geometry/epilogue identical):
//  - K-loop: ONE raw barrier per step (was 2 + hard fences). Sequence:
//      vmcnt(0) -> s_barrier -> stage(s+1) -> ds_read cur -> MFMA cur
//    2 LDS buffers. Safety: buf cur^1 was read at step s-1 and each wave's
//    MFMAs lgkm-wait on those reads before it reaches the barrier, so at
//    barrier exit the old buffer is dead and stage(s+1) may overwrite it.
//    No mid-step barrier / lgkmcnt(0) drain -> compiler interleaves
//    ds_reads with MFMAs (fine-grained lgkmcnt), waves slip in the window.
//  - __syncthreads() at epilogue top replaces the hazard cover the removed
//    mid-step barrier provided (K-step act reads vs in-place act writes).
//  - out stores are non-temporal (out never re-read; kills write-allocate
//    traffic: WRITE_SIZE was 1.65x data, FETCH had ~60MB read-allocate).
// Grid: 256 blocks (1/CU) x 512 threads. 2 dispatches total.

#define BROWS 16384
#define DIM 512
#define NL 4
#define OUTSTRIDE (NL * DIM)

#define BM 64
#define BK 32
#define SEG (DIM / BK)        // 16 K-steps per layer
#define NSTEP (NL * SEG)      // 64 global K-steps

typedef unsigned short ushort_t;
typedef __attribute__((ext_vector_type(8))) short bf16x8;
typedef __attribute__((ext_vector_type(4))) float f32x4;

__device__ inline ushort_t f32_to_bf16(float f) {
    union { float f; uint32_t u; } v; v.f = f;
    uint32_t u = v.u;
    uint32_t r = (u + 0x7fffu + ((u >> 16) & 1u)) >> 16;   // RNE
    return (ushort_t)r;
}

__device__ inline float bf16_lo(uint32_t p) {   // low bf16 of packed pair
    union { uint32_t u; float f; } v; v.u = p << 16; return v.f;
}
__device__ inline float bf16_hi(uint32_t p) {   // high bf16 of packed pair
    union { uint32_t u; float f; } v; v.u = p & 0xffff0000u; return v.f;
}

__device__ inline float wave_reduce_sum(float v) {
    #pragma unroll
    for (int off = 32; off > 0; off >>= 1) v += __shfl_down(v, off, 64);
    return v;
}

// ---------------------------------------------------------------------------
// prep: W f32 -> bf16 + wsum[l][e] = sum_d W[l][e][d]. 2048 blocks x 256.
// ---------------------------------------------------------------------------
__global__ __launch_bounds__(256) void prep_kernel(
    const float* __restrict__ W, ushort_t* __restrict__ Wb,
    float* __restrict__ wsum)
{
    int row = blockIdx.x;      // l*512 + e
    int t = threadIdx.x;
    const float* wp = W + (size_t)row * DIM;
    float f0 = wp[2 * t], f1 = wp[2 * t + 1];
    ushort_t* wbp = Wb + (size_t)row * DIM;
    wbp[2 * t]     = f32_to_bf16(f0);
    wbp[2 * t + 1] = f32_to_bf16(f1);
    __shared__ float red[4];
    int wave = t >> 6, lane = t & 63;
    float r = wave_reduce_sum(f0 + f1);
    if (lane == 0) red[wave] = r;
    __syncthreads();
    if (t == 0) wsum[row] = red[0] + red[1] + red[2] + red[3];
}

// ---------------------------------------------------------------------------
// fused main kernel
// ---------------------------------------------------------------------------
__global__ __launch_bounds__(512, 1) void cross_kernel(
    const float* __restrict__ x0,
    const ushort_t* __restrict__ Wb,    // [4][512][512] bf16 bits
    const float* __restrict__ bias,     // [4][512]
    const float* __restrict__ wsum,     // [4][512]
    float* __restrict__ out)            // [16384][2048]
{
    // act: [64 rows][512 cols] bf16, chunk-swizzled: 16B-chunk kc at
    //   elem = row*512 + ((kc ^ (row&7))<<3) + (col&7)
    __shared__ __align__(16) ushort_t sAct[BM * DIM];        // 64 KB
    __shared__ __align__(16) ushort_t sB[2][DIM * BK];       // 2 x 32 KB
    __shared__ float sRed[4][4][BM];                          // 4 KB
    __shared__ float sSums[4][BM];                            // 1 KB
    __shared__ float sCn[BM];

    int tid  = threadIdx.x;
    int wave = tid >> 6;
    int lane = tid & 63;
    int wm  = wave >> 2;       // 0..1: 32-row half
    int wn4 = wave & 3;        // 0..3: 128-col quarter
    int q = lane >> 4;         // 0..3
    int rr = lane & 15;
    int nlane = lane & 15;
    int bm = blockIdx.x * BM;

    // per-lane pre-swizzled B source offsets (elements), 4 chunk-calls/stage
    int beoff[4];
    #pragma unroll
    for (int j = 0; j < 4; ++j) {
        int brow = wave * 64 + j * 16 + (lane >> 2);   // W-row 0..511
        int chunk = (lane & 3) ^ (brow & 3);
        beoff[j] = brow * DIM + chunk * 8;
    }

    auto stageB = [&](int s) {    // global step s: layer s>>4, k0 = (s&15)*BK
        int cur = s & 1;
        const ushort_t* gb = Wb + (size_t)(s >> 4) * DIM * DIM + (s & 15) * BK;
        #pragma unroll
        for (int j = 0; j < 4; ++j) {
            __builtin_amdgcn_global_load_lds(
                (const __attribute__((address_space(1))) void*)(gb + beoff[j]),
                (__attribute__((address_space(3))) void*)(&sB[cur][(wave * 64 + j * 16) * BK]),
                16, 0, 0);
        }
    };

    stageB(0);   // buf0 in flight under the x0 phase

    // ---- x0 phase: stage rows into act (swizzled bf16) + sums[0] ----
    #pragma unroll
    for (int r8 = 0; r8 < 8; ++r8) {
        int row = wave * 8 + r8;
        const float* xp = x0 + (size_t)(bm + row) * DIM + lane * 8;
        float4 a = ((const float4*)xp)[0];
        float4 b4 = ((const float4*)xp)[1];
        float f[8] = {a.x, a.y, a.z, a.w, b4.x, b4.y, b4.z, b4.w};
        bf16x8 o;
        float s = 0.f;
        #pragma unroll
        for (int i = 0; i < 8; ++i) { o[i] = (short)f32_to_bf16(f[i]); s += f[i]; }
        int kc = lane ^ (row & 7);                 // logical chunk = lane
        *(bf16x8*)(&sAct[row * DIM + kc * 8]) = o;
        s = wave_reduce_sum(s);
        if (lane == 0) sSums[0][row] = s;
    }
    __syncthreads();

    // dot-operand register keeps (packed bf16 pairs at C-layout positions)
    uint32_t vk0[32], vk1[32], vk2[32];

    #pragma unroll
    for (int l = 0; l < NL; ++l) {
        f32x4 acc[2][8] = {};

        for (int t = 0; t < SEG; ++t) {
            int s = l * SEG + t;
            int cur = s & 1;
            // my stage(s) loads (issued one step ago) retired -> after the
            // barrier, every wave's stage(s) writes are visible and the
            // other buffer is dead (its readers' MFMAs lgkm-waited pre-barrier)
            asm volatile("s_waitcnt vmcnt(0)" ::: "memory");
            __builtin_amdgcn_s_barrier();
            if (s + 1 < NSTEP) stageB(s + 1);   // into buf cur^1, depth-1

            bf16x8 af[2], bfr[8];
            #pragma unroll
            for (int mi = 0; mi < 2; ++mi) {
                int arow = wm * 32 + mi * 16 + rr;
                int kc = (t * 4 + q) ^ (arow & 7);
                af[mi] = *(const bf16x8*)(&sAct[arow * DIM + kc * 8]);
            }
            int ch2 = q ^ (rr & 3);
            #pragma unroll
            for (int ni = 0; ni < 8; ++ni) {
                int erow = wn4 * 128 + ni * 16 + rr;
                bfr[ni] = *(const bf16x8*)(&sB[cur][erow * BK + ch2 * 8]);
            }
            #pragma unroll
            for (int mi = 0; mi < 2; ++mi)
                #pragma unroll
                for (int ni = 0; ni < 8; ++ni)
                    acc[mi][ni] = __builtin_amdgcn_mfma_f32_16x16x32_bf16(
                        af[mi], bfr[ni], acc[mi][ni], 0, 0, 0);
        }

        // all waves' last-step act reads consumed before in-place act writes
        __syncthreads();

        // ---------------- epilogue layer l ----------------
        float ws8[8], bs8[8];
        #pragma unroll
        for (int ni = 0; ni < 8; ++ni) {
            int ng = wn4 * 128 + ni * 16 + nlane;
            ws8[ni] = wsum[l * DIM + ng];
            bs8[ni] = bias[l * DIM + ng];
        }
        float cl8[8];
        #pragma unroll
        for (int mi = 0; mi < 2; ++mi)
            #pragma unroll
            for (int r = 0; r < 4; ++r)
                cl8[mi * 4 + r] = (l == 0) ? 0.f : sCn[wm * 32 + mi * 16 + q * 4 + r];

        if (l == 0) {
            // capture x0 at this thread's C-positions (before in-place x1 write)
            #pragma unroll
            for (int mi = 0; mi < 2; ++mi)
                #pragma unroll
                for (int r = 0; r < 4; ++r) {
                    int row = wm * 32 + mi * 16 + q * 4 + r;
                    #pragma unroll
                    for (int nip = 0; nip < 4; ++nip) {
                        int kc0 = (wn4 * 16 + 4 * nip + (nlane >> 3)) ^ (row & 7);
                        int kc1 = (wn4 * 16 + 4 * nip + 2 + (nlane >> 3)) ^ (row & 7);
                        uint32_t b0 = sAct[row * DIM + kc0 * 8 + (nlane & 7)];
                        uint32_t b1 = sAct[row * DIM + kc1 * 8 + (nlane & 7)];
                        vk0[(mi * 4 + r) * 4 + nip] = b0 | (b1 << 16);
                    }
                }
        }

        #pragma unroll
        for (int mi = 0; mi < 2; ++mi)
            #pragma unroll
            for (int r = 0; r < 4; ++r) {
                int mr = mi * 4 + r;
                int row = wm * 32 + mi * 16 + q * 4 + r;
                float cc = cl8[mr];
                float vv[8];
                #pragma unroll
                for (int ni = 0; ni < 8; ++ni) {
                    vv[ni] = acc[mi][ni][r] + cc * ws8[ni] + bs8[ni];
                    int colg = wn4 * 128 + ni * 16 + nlane;
                    __builtin_nontemporal_store(
                        vv[ni], &out[(size_t)(bm + row) * OUTSTRIDE + l * DIM + colg]);
                }
                if (l < 3) {
                    float vs = 0.f, d0 = 0.f, d1 = 0.f, d2 = 0.f;
                    #pragma unroll
                    for (int ni = 0; ni < 8; ++ni) vs += vv[ni];
                    #pragma unroll
                    for (int nip = 0; nip < 4; ++nip) {
                        uint32_t p0 = vk0[mr * 4 + nip];
                        d0 += vv[2 * nip] * bf16_lo(p0) + vv[2 * nip + 1] * bf16_hi(p0);
                        if (l >= 1) {
                            uint32_t p1 = vk1[mr * 4 + nip];
                            d1 += vv[2 * nip] * bf16_lo(p1) + vv[2 * nip + 1] * bf16_hi(p1);
                        }
                        if (l >= 2) {
                            uint32_t p2 = vk2[mr * 4 + nip];
                            d2 += vv[2 * nip] * bf16_lo(p2) + vv[2 * nip + 1] * bf16_hi(p2);
                        }
                    }
                    // in-place act write (x_{l+1}) + register keep
                    #pragma unroll
                    for (int nip = 0; nip < 4; ++nip) {
                        ushort_t h0 = f32_to_bf16(vv[2 * nip]);
                        ushort_t h1 = f32_to_bf16(vv[2 * nip + 1]);
                        int kc0 = (wn4 * 16 + 4 * nip + (nlane >> 3)) ^ (row & 7);
                        int kc1 = (wn4 * 16 + 4 * nip + 2 + (nlane >> 3)) ^ (row & 7);
                        sAct[row * DIM + kc0 * 8 + (nlane & 7)] = h0;
                        sAct[row * DIM + kc1 * 8 + (nlane & 7)] = h1;
                        uint32_t pk = (uint32_t)h0 | ((uint32_t)h1 << 16);
                        if (l == 0) vk1[mr * 4 + nip] = pk;
                        if (l == 1) vk2[mr * 4 + nip] = pk;
                    }
                    #pragma unroll
                    for (int off = 8; off > 0; off >>= 1) {
                        vs += __shfl_xor(vs, off, 64);
                        d0 += __shfl_xor(d0, off, 64);
                        if (l >= 1) d1 += __shfl_xor(d1, off, 64);
                        if (l >= 2) d2 += __shfl_xor(d2, off, 64);
                    }
                    if (nlane == 0) {
                        sRed[0][wn4][row] = vs;
                        sRed[1][wn4][row] = d0;
                        if (l >= 1) sRed[2][wn4][row] = d1;
                        if (l >= 2) sRed[3][wn4][row] = d2;
                    }
                }
            }

        if (l < 3) {
            __syncthreads();
            if (tid < BM) {
                float vs = sRed[0][0][tid] + sRed[0][1][tid] + sRed[0][2][tid] + sRed[0][3][tid];
                float d0 = sRed[1][0][tid] + sRed[1][1][tid] + sRed[1][2][tid] + sRed[1][3][tid];
                float c = d0;                                   // j=0: c = 0 + d0 + 0*s0
                if (l >= 1) {
                    float d1 = sRed[2][0][tid] + sRed[2][1][tid] + sRed[2][2][tid] + sRed[2][3][tid];
                    c = c + d1 + c * sSums[1][tid];
                }
                if (l >= 2) {
                    float d2 = sRed[3][0][tid] + sRed[3][1][tid] + sRed[3][2][tid] + sRed[3][3][tid];
                    c = c + d2 + c * sSums[2][tid];
                }
                sCn[tid] = c;
                sSums[l + 1][tid] = vs;
            }
            __syncthreads();
        }
    }
}

// ---------------------------------------------------------------------------
extern "C" void kernel_launch(void* const* d_in, const int* in_sizes, int n_in,
                              void* d_out, int out_size, void* d_ws, size_t ws_size,
                              hipStream_t stream) {
    (void)in_sizes; (void)n_in; (void)out_size; (void)ws_size;
    const float* x0   = (const float*)d_in[0];
    const float* W    = (const float*)d_in[1];
    const float* bias = (const float*)d_in[2];
    float* out = (float*)d_out;

    char* ws = (char*)d_ws;
    // workspace: Wb 4*512*512*2 = 2,097,152 @ 0; wsum 4*512*4 = 8,192 @ 2,097,152
    ushort_t* Wb   = (ushort_t*)ws;
    float*    wsum = (float*)(ws + 2097152);

    prep_kernel<<<NL * DIM, 256, 0, stream>>>(W, Wb, wsum);
    cross_kernel<<<BROWS / BM, 512, 0, stream>>>(x0, Wb, bias, wsum, out);
}

// Round 6
// 265.480 us; speedup vs baseline: 1.0935x; 1.0507x over previous
//
#include <hip/hip_runtime.h>
#include <stdint.h>

// CrossNetwork fused: x:[16384,512] f32, W:[4,512,512] f32, b:[4,512] f32
// out:[16384,2048] f32 = concat(x1..x4).
//
// Algebra: residual loop collapses to x_eff = x_l + c_l*1 with
//   c = 0; for j<l: c = c + dot(x_l,x_j) + c*sum(x_j)
// and (x_l + c*1)@W^T = x_l@W^T + c*rowsum(W).
//
// R8 = R7 resubmit (container failed; likely infra) + fixes:
//  - 1024 threads/block = 16 waves = 4 waves/SIMD (R6 showed 22.7% occupancy
//    with EVERYTHING idle -> latency-serialized at 2 waves/SIMD).
//    Wave grid 2x8: per wave af[2], bfr[4], 8 MFMA/step; ~115 VGPR fits the
//    128-reg cap implied by a 16-wave block.
//  - sB staging RE-ADDS the pre-swizzled global source (chunk ^= row&3,
//    linear LDS dest, same XOR on read) that R7 dropped: without it every
//    bfr ds_read_b128 is a ~4-way bank conflict (64B row stride).
//  - sAct swizzle row&15 XOR; epilogue reads x_l from sAct before the
//    in-place overwrite (doubles as the vk0/vk1 capture).
// Grid: 256 blocks (1/CU) x 1024 threads. 2 dispatches total.

#define BROWS 16384
#define DIM 512
#define NL 4
#define OUTSTRIDE (NL * DIM)

#define BM 64
#define BK 32
#define SEG (DIM / BK)        // 16 K-steps per layer
#define NSTEP (NL * SEG)      // 64 global K-steps

typedef unsigned short ushort_t;
typedef __attribute__((ext_vector_type(8))) short bf16x8;
typedef __attribute__((ext_vector_type(4))) float f32x4;

__device__ inline ushort_t f32_to_bf16(float f) {
    union { float f; uint32_t u; } v; v.f = f;
    uint32_t u = v.u;
    uint32_t r = (u + 0x7fffu + ((u >> 16) & 1u)) >> 16;   // RNE
    return (ushort_t)r;
}

__device__ inline float bf16_bits_to_f32(ushort_t u) {
    union { uint32_t u; float f; } v; v.u = ((uint32_t)u) << 16; return v.f;
}

__device__ inline float bf16_lo(uint32_t p) {
    union { uint32_t u; float f; } v; v.u = p << 16; return v.f;
}
__device__ inline float bf16_hi(uint32_t p) {
    union { uint32_t u; float f; } v; v.u = p & 0xffff0000u; return v.f;
}

__device__ inline float wave_reduce_sum(float v) {
    #pragma unroll
    for (int off = 32; off > 0; off >>= 1) v += __shfl_down(v, off, 64);
    return v;
}

// ---------------------------------------------------------------------------
// prep: W f32 -> bf16 + wsum[l][e] = sum_d W[l][e][d]. 2048 blocks x 256.
// ---------------------------------------------------------------------------
__global__ __launch_bounds__(256) void prep_kernel(
    const float* __restrict__ W, ushort_t* __restrict__ Wb,
    float* __restrict__ wsum)
{
    int row = blockIdx.x;      // l*512 + e
    int t = threadIdx.x;
    const float* wp = W + (size_t)row * DIM;
    float f0 = wp[2 * t], f1 = wp[2 * t + 1];
    ushort_t* wbp = Wb + (size_t)row * DIM;
    wbp[2 * t]     = f32_to_bf16(f0);
    wbp[2 * t + 1] = f32_to_bf16(f1);
    __shared__ float red[4];
    int wave = t >> 6, lane = t & 63;
    float r = wave_reduce_sum(f0 + f1);
    if (lane == 0) red[wave] = r;
    __syncthreads();
    if (t == 0) wsum[row] = red[0] + red[1] + red[2] + red[3];
}

// ---------------------------------------------------------------------------
// fused main kernel: 16 waves (2 wm x 8 wn8), BM=64 rows per block
// ---------------------------------------------------------------------------
__global__ __launch_bounds__(1024) void cross_kernel(
    const float* __restrict__ x0,
    const ushort_t* __restrict__ Wb,    // [4][512][512] bf16 bits
    const float* __restrict__ bias,     // [4][512]
    const float* __restrict__ wsum,     // [4][512]
    float* __restrict__ out)            // [16384][2048]
{
    // act: [64 rows][512 cols] bf16, 16B-chunk swizzle: chunk kc stored at
    //   elem = row*512 + ((kc ^ (row&15))<<3) + (col&7)
    // sB:  [512 W-rows][32 k] bf16, 16B-chunk swizzle within row:
    //   LDS chunk c of row R holds GLOBAL chunk c ^ (R&3)  (pre-swz source)
    __shared__ __align__(16) ushort_t sAct[BM * DIM];        // 64 KB
    __shared__ __align__(16) ushort_t sB[2][DIM * BK];       // 2 x 32 KB
    __shared__ float sRed[4][8][BM];                          // 8 KB
    __shared__ float sSums[NL][BM];                           // 1 KB
    __shared__ float sCn[BM];

    const int tid  = threadIdx.x;
    const int wave = tid >> 6;     // 0..15
    const int lane = tid & 63;
    const int wm   = wave >> 3;    // 0..1: 32-row half
    const int wn8  = wave & 7;     // 0..7: 64-col eighth
    const int q    = lane >> 4;    // 0..3
    const int rr   = lane & 15;
    const int nlane = lane & 15;
    const int bm   = blockIdx.x * BM;

    // staging: lane covers (srow, chunk lane&3); source chunk pre-swizzled
    const int srow = lane >> 2;          // 0..15

    auto stageB = [&](int s) {    // global step s: layer s>>4, k0 = (s&15)*BK
        const ushort_t* gb = Wb + (size_t)(s >> 4) * (DIM * DIM) + (s & 15) * BK;
        #pragma unroll
        for (int c = 0; c < 2; ++c) {
            int r0 = wave * 32 + c * 16;
            int grow = r0 + srow;
            int gchunk = (lane & 3) ^ (grow & 3);      // pre-swizzled source
            __builtin_amdgcn_global_load_lds(
                (const __attribute__((address_space(1))) void*)(gb + (size_t)grow * DIM + gchunk * 8),
                (__attribute__((address_space(3))) void*)(&sB[s & 1][r0 * BK]), 16, 0, 0);
        }
    };

    stageB(0);   // in flight under the x0 phase

    // ---- x0 phase: 4 rows/wave into swizzled act + sums[0] ----
    #pragma unroll
    for (int r4 = 0; r4 < 4; ++r4) {
        int row = wave * 4 + r4;
        const float* xp = x0 + (size_t)(bm + row) * DIM + lane * 8;
        float4 a = ((const float4*)xp)[0];
        float4 b4 = ((const float4*)xp)[1];
        float f[8] = {a.x, a.y, a.z, a.w, b4.x, b4.y, b4.z, b4.w};
        bf16x8 o;
        float s = 0.f;
        #pragma unroll
        for (int i = 0; i < 8; ++i) { o[i] = (short)f32_to_bf16(f[i]); s += f[i]; }
        int kc = lane ^ (row & 15);
        *(bf16x8*)(&sAct[row * DIM + kc * 8]) = o;
        s = wave_reduce_sum(s);
        if (lane == 0) sSums[0][row] = s;
    }
    __syncthreads();

    // register keeps of x0, x1 at this thread's C-positions (packed bf16 pairs)
    uint32_t vk0[16], vk1[16];

    #pragma unroll
    for (int l = 0; l < NL; ++l) {
        f32x4 acc[2][4] = {};

        for (int t = 0; t < SEG; ++t) {
            int s = l * SEG + t;
            // stage(s) (issued one step ago) retired for THIS wave; after the
            // barrier all waves' stage(s) are visible and buf s^1 is dead
            // (its readers' MFMAs lgkm-waited before reaching the barrier).
            asm volatile("s_waitcnt vmcnt(0)" ::: "memory");
            __builtin_amdgcn_s_barrier();
            if (s + 1 < NSTEP) stageB(s + 1);

            bf16x8 af[2], bfr[4];
            #pragma unroll
            for (int mi = 0; mi < 2; ++mi) {
                int row = wm * 32 + mi * 16 + rr;
                int kc = (4 * t + q) ^ (row & 15);
                af[mi] = *(const bf16x8*)(&sAct[row * DIM + kc * 8]);
            }
            #pragma unroll
            for (int ni = 0; ni < 4; ++ni) {
                int erow = wn8 * 64 + ni * 16 + rr;
                int bc = q ^ (erow & 3);               // un-swizzle on read
                bfr[ni] = *(const bf16x8*)(&sB[s & 1][erow * BK + bc * 8]);
            }
            #pragma unroll
            for (int mi = 0; mi < 2; ++mi)
                #pragma unroll
                for (int ni = 0; ni < 4; ++ni)
                    acc[mi][ni] = __builtin_amdgcn_mfma_f32_16x16x32_bf16(
                        af[mi], bfr[ni], acc[mi][ni], 0, 0, 0);
        }

        // all waves' K-loop act reads done before in-place act writes
        __syncthreads();

        // ---------------- epilogue layer l ----------------
        // C/D layout (verified m89/m91): col = lane&15, row = (lane>>4)*4 + reg
        float ws4[4], bs4[4];
        #pragma unroll
        for (int ni = 0; ni < 4; ++ni) {
            int ng = wn8 * 64 + ni * 16 + nlane;
            ws4[ni] = wsum[l * DIM + ng];
            bs4[ni] = bias[l * DIM + ng];
        }

        #pragma unroll
        for (int mi = 0; mi < 2; ++mi)
            #pragma unroll
            for (int r = 0; r < 4; ++r) {
                const int mr = mi * 4 + r;
                const int row = wm * 32 + mi * 16 + q * 4 + r;
                float cc = (l == 0) ? 0.f : sCn[row];
                float vv[4];
                #pragma unroll
                for (int ni = 0; ni < 4; ++ni) {
                    vv[ni] = acc[mi][ni][r] + cc * ws4[ni] + bs4[ni];
                    int colg = wn8 * 64 + ni * 16 + nlane;
                    out[(size_t)(bm + row) * OUTSTRIDE + l * DIM + colg] = vv[ni];
                }
                if (l < 3) {
                    // read x_l at my positions from sAct (before overwrite);
                    // doubles as the capture for vk0 (l=0) / vk1 (l=1)
                    ushort_t xl[4];
                    #pragma unroll
                    for (int ni = 0; ni < 4; ++ni) {
                        int cg = wn8 * 8 + ni * 2 + (nlane >> 3);
                        int kc = cg ^ (row & 15);
                        xl[ni] = sAct[row * DIM + kc * 8 + (nlane & 7)];
                    }
                    float vs = 0.f, dc = 0.f;
                    #pragma unroll
                    for (int ni = 0; ni < 4; ++ni) {
                        vs += vv[ni];
                        dc += vv[ni] * bf16_bits_to_f32(xl[ni]);
                    }
                    float d0 = 0.f, d1 = 0.f, d2 = 0.f;
                    if (l == 0) {
                        d0 = dc;
                        #pragma unroll
                        for (int nip = 0; nip < 2; ++nip)
                            vk0[mr * 2 + nip] =
                                (uint32_t)xl[2 * nip] | ((uint32_t)xl[2 * nip + 1] << 16);
                    } else {
                        #pragma unroll
                        for (int nip = 0; nip < 2; ++nip) {
                            uint32_t p = vk0[mr * 2 + nip];
                            d0 += vv[2 * nip] * bf16_lo(p) + vv[2 * nip + 1] * bf16_hi(p);
                        }
                        if (l == 1) {
                            d1 = dc;
                            #pragma unroll
                            for (int nip = 0; nip < 2; ++nip)
                                vk1[mr * 2 + nip] =
                                    (uint32_t)xl[2 * nip] | ((uint32_t)xl[2 * nip + 1] << 16);
                        } else {   // l == 2
                            #pragma unroll
                            for (int nip = 0; nip < 2; ++nip) {
                                uint32_t p = vk1[mr * 2 + nip];
                                d1 += vv[2 * nip] * bf16_lo(p) + vv[2 * nip + 1] * bf16_hi(p);
                            }
                            d2 = dc;
                        }
                    }
                    // in-place act write: x_{l+1}
                    #pragma unroll
                    for (int ni = 0; ni < 4; ++ni) {
                        int cg = wn8 * 8 + ni * 2 + (nlane >> 3);
                        int kc = cg ^ (row & 15);
                        sAct[row * DIM + kc * 8 + (nlane & 7)] = f32_to_bf16(vv[ni]);
                    }
                    // 16-lane reduce
                    #pragma unroll
                    for (int off = 8; off > 0; off >>= 1) {
                        vs += __shfl_xor(vs, off, 64);
                        d0 += __shfl_xor(d0, off, 64);
                        if (l >= 1) d1 += __shfl_xor(d1, off, 64);
                        if (l >= 2) d2 += __shfl_xor(d2, off, 64);
                    }
                    if (nlane == 0) {
                        sRed[0][wn8][row] = vs;
                        sRed[1][wn8][row] = d0;
                        if (l >= 1) sRed[2][wn8][row] = d1;
                        if (l >= 2) sRed[3][wn8][row] = d2;
                    }
                }
            }

        if (l < 3) {
            __syncthreads();
            if (tid < BM) {
                float vs = 0.f, d0 = 0.f;
                #pragma unroll
                for (int g = 0; g < 8; ++g) { vs += sRed[0][g][tid]; d0 += sRed[1][g][tid]; }
                float c = d0;                                   // j=0: c = 0 + d0 + 0*s0
                if (l >= 1) {
                    float d1 = 0.f;
                    #pragma unroll
                    for (int g = 0; g < 8; ++g) d1 += sRed[2][g][tid];
                    c = c + d1 + c * sSums[1][tid];
                }
                if (l >= 2) {
                    float d2 = 0.f;
                    #pragma unroll
                    for (int g = 0; g < 8; ++g) d2 += sRed[3][g][tid];
                    c = c + d2 + c * sSums[2][tid];
                }
                sCn[tid] = c;
                sSums[l + 1][tid] = vs;
            }
            __syncthreads();
        }
    }
}

// ---------------------------------------------------------------------------
extern "C" void kernel_launch(void* const* d_in, const int* in_sizes, int n_in,
                              void* d_out, int out_size, void* d_ws, size_t ws_size,
                              hipStream_t stream) {
    (void)in_sizes; (void)n_in; (void)out_size; (void)ws_size;
    const float* x0   = (const float*)d_in[0];
    const float* W    = (const float*)d_in[1];
    const float* bias = (const float*)d_in[2];
    float* out = (float*)d_out;

    char* ws = (char*)d_ws;
    // workspace: Wb 4*512*512*2 = 2,097,152 @ 0; wsum 4*512*4 = 8,192 @ 2,097,152
    ushort_t* Wb   = (ushort_t*)ws;
    float*    wsum = (float*)(ws + 2097152);

    prep_kernel<<<NL * DIM, 256, 0, stream>>>(W, Wb, wsum);
    cross_kernel<<<BROWS / BM, 1024, 0, stream>>>(x0, Wb, bias, wsum, out);
}

// Round 7
// 264.846 us; speedup vs baseline: 1.0961x; 1.0024x over previous
//
#include <hip/hip_runtime.h>
#include <stdint.h>

// CrossNetwork fused: x:[16384,512] f32, W:[4,512,512] f32, b:[4,512] f32
// out:[16384,2048] f32 = concat(x1..x4).
//
// Algebra: residual loop collapses to x_eff = x_l + c_l*1 with
//   c = 0; for j<l: c = c + dot(x_l,x_j) + c*sum(x_j)
// and (x_l + c*1)@W^T = x_l@W^T + c*rowsum(W).
//
// R9 = R8 + __launch_bounds__(1024, 4).
//   R8's counter CSV showed VGPR_Count=64: without the min-waves arg, hipcc
//   capped a 1024-thread block at 64 VGPRs -> acc+vk spilled to scratch.
//   Evidence: FETCH 119MB (=35.5 real + ~84 spill), WRITE 225MB (=134 real
//   + ~91 spill), 4800 cy/step vs ~600 cy of real work, all pipes <13% busy.
//   (1024,4) -> 4 waves/EU -> 128-VGPR cap; per-thread state ~110 regs fits.
//   R5/R6 were also spill-bound (state >160 regs at 128 cap) - the fused
//   design was never actually latency-bound, it was scratch-bound.
// Structure (unchanged from R8):
//  - 256 blocks (1/CU) x 1024 threads (16 waves = 2 wm x 8 wn8), BM=64 rows.
//  - sAct 64KB swizzled (kc ^ row&15), in-place layer update; vk0/vk1
//    register keeps of x0/x1 at C-positions; dots fused into epilogue.
//  - sB 2x32KB double-buffer, pre-swizzled global source (chunk ^ row&3),
//    K-loop: vmcnt(0) -> s_barrier -> stage(s+1) -> ds_read -> 8 MFMA.
// 2 dispatches total.

#define BROWS 16384
#define DIM 512
#define NL 4
#define OUTSTRIDE (NL * DIM)

#define BM 64
#define BK 32
#define SEG (DIM / BK)        // 16 K-steps per layer
#define NSTEP (NL * SEG)      // 64 global K-steps

typedef unsigned short ushort_t;
typedef __attribute__((ext_vector_type(8))) short bf16x8;
typedef __attribute__((ext_vector_type(4))) float f32x4;

__device__ inline ushort_t f32_to_bf16(float f) {
    union { float f; uint32_t u; } v; v.f = f;
    uint32_t u = v.u;
    uint32_t r = (u + 0x7fffu + ((u >> 16) & 1u)) >> 16;   // RNE
    return (ushort_t)r;
}

__device__ inline float bf16_bits_to_f32(ushort_t u) {
    union { uint32_t u; float f; } v; v.u = ((uint32_t)u) << 16; return v.f;
}

__device__ inline float bf16_lo(uint32_t p) {
    union { uint32_t u; float f; } v; v.u = p << 16; return v.f;
}
__device__ inline float bf16_hi(uint32_t p) {
    union { uint32_t u; float f; } v; v.u = p & 0xffff0000u; return v.f;
}

__device__ inline float wave_reduce_sum(float v) {
    #pragma unroll
    for (int off = 32; off > 0; off >>= 1) v += __shfl_down(v, off, 64);
    return v;
}

// ---------------------------------------------------------------------------
// prep: W f32 -> bf16 + wsum[l][e] = sum_d W[l][e][d]. 2048 blocks x 256.
// ---------------------------------------------------------------------------
__global__ __launch_bounds__(256) void prep_kernel(
    const float* __restrict__ W, ushort_t* __restrict__ Wb,
    float* __restrict__ wsum)
{
    int row = blockIdx.x;      // l*512 + e
    int t = threadIdx.x;
    const float* wp = W + (size_t)row * DIM;
    float f0 = wp[2 * t], f1 = wp[2 * t + 1];
    ushort_t* wbp = Wb + (size_t)row * DIM;
    wbp[2 * t]     = f32_to_bf16(f0);
    wbp[2 * t + 1] = f32_to_bf16(f1);
    __shared__ float red[4];
    int wave = t >> 6, lane = t & 63;
    float r = wave_reduce_sum(f0 + f1);
    if (lane == 0) red[wave] = r;
    __syncthreads();
    if (t == 0) wsum[row] = red[0] + red[1] + red[2] + red[3];
}

// ---------------------------------------------------------------------------
// fused main kernel: 16 waves (2 wm x 8 wn8), BM=64 rows per block
// ---------------------------------------------------------------------------
__global__ __launch_bounds__(1024, 4) void cross_kernel(
    const float* __restrict__ x0,
    const ushort_t* __restrict__ Wb,    // [4][512][512] bf16 bits
    const float* __restrict__ bias,     // [4][512]
    const float* __restrict__ wsum,     // [4][512]
    float* __restrict__ out)            // [16384][2048]
{
    // act: [64 rows][512 cols] bf16, 16B-chunk swizzle: chunk kc stored at
    //   elem = row*512 + ((kc ^ (row&15))<<3) + (col&7)
    // sB:  [512 W-rows][32 k] bf16, 16B-chunk swizzle within row:
    //   LDS chunk c of row R holds GLOBAL chunk c ^ (R&3)  (pre-swz source)
    __shared__ __align__(16) ushort_t sAct[BM * DIM];        // 64 KB
    __shared__ __align__(16) ushort_t sB[2][DIM * BK];       // 2 x 32 KB
    __shared__ float sRed[4][8][BM];                          // 8 KB
    __shared__ float sSums[NL][BM];                           // 1 KB
    __shared__ float sCn[BM];

    const int tid  = threadIdx.x;
    const int wave = tid >> 6;     // 0..15
    const int lane = tid & 63;
    const int wm   = wave >> 3;    // 0..1: 32-row half
    const int wn8  = wave & 7;     // 0..7: 64-col eighth
    const int q    = lane >> 4;    // 0..3
    const int rr   = lane & 15;
    const int nlane = lane & 15;
    const int bm   = blockIdx.x * BM;

    // staging: lane covers (srow, chunk lane&3); source chunk pre-swizzled
    const int srow = lane >> 2;          // 0..15

    auto stageB = [&](int s) {    // global step s: layer s>>4, k0 = (s&15)*BK
        const ushort_t* gb = Wb + (size_t)(s >> 4) * (DIM * DIM) + (s & 15) * BK;
        #pragma unroll
        for (int c = 0; c < 2; ++c) {
            int r0 = wave * 32 + c * 16;
            int grow = r0 + srow;
            int gchunk = (lane & 3) ^ (grow & 3);      // pre-swizzled source
            __builtin_amdgcn_global_load_lds(
                (const __attribute__((address_space(1))) void*)(gb + (size_t)grow * DIM + gchunk * 8),
                (__attribute__((address_space(3))) void*)(&sB[s & 1][r0 * BK]), 16, 0, 0);
        }
    };

    stageB(0);   // in flight under the x0 phase

    // ---- x0 phase: 4 rows/wave into swizzled act + sums[0] ----
    #pragma unroll
    for (int r4 = 0; r4 < 4; ++r4) {
        int row = wave * 4 + r4;
        const float* xp = x0 + (size_t)(bm + row) * DIM + lane * 8;
        float4 a = ((const float4*)xp)[0];
        float4 b4 = ((const float4*)xp)[1];
        float f[8] = {a.x, a.y, a.z, a.w, b4.x, b4.y, b4.z, b4.w};
        bf16x8 o;
        float s = 0.f;
        #pragma unroll
        for (int i = 0; i < 8; ++i) { o[i] = (short)f32_to_bf16(f[i]); s += f[i]; }
        int kc = lane ^ (row & 15);
        *(bf16x8*)(&sAct[row * DIM + kc * 8]) = o;
        s = wave_reduce_sum(s);
        if (lane == 0) sSums[0][row] = s;
    }
    __syncthreads();

    // register keeps of x0, x1 at this thread's C-positions (packed bf16 pairs)
    uint32_t vk0[16], vk1[16];

    #pragma unroll
    for (int l = 0; l < NL; ++l) {
        f32x4 acc[2][4] = {};

        for (int t = 0; t < SEG; ++t) {
            int s = l * SEG + t;
            // stage(s) (issued one step ago) retired for THIS wave; after the
            // barrier all waves' stage(s) are visible and buf s^1 is dead
            // (its readers' MFMAs lgkm-waited before reaching the barrier).
            asm volatile("s_waitcnt vmcnt(0)" ::: "memory");
            __builtin_amdgcn_s_barrier();
            if (s + 1 < NSTEP) stageB(s + 1);

            bf16x8 af[2], bfr[4];
            #pragma unroll
            for (int mi = 0; mi < 2; ++mi) {
                int row = wm * 32 + mi * 16 + rr;
                int kc = (4 * t + q) ^ (row & 15);
                af[mi] = *(const bf16x8*)(&sAct[row * DIM + kc * 8]);
            }
            #pragma unroll
            for (int ni = 0; ni < 4; ++ni) {
                int erow = wn8 * 64 + ni * 16 + rr;
                int bc = q ^ (erow & 3);               // un-swizzle on read
                bfr[ni] = *(const bf16x8*)(&sB[s & 1][erow * BK + bc * 8]);
            }
            #pragma unroll
            for (int mi = 0; mi < 2; ++mi)
                #pragma unroll
                for (int ni = 0; ni < 4; ++ni)
                    acc[mi][ni] = __builtin_amdgcn_mfma_f32_16x16x32_bf16(
                        af[mi], bfr[ni], acc[mi][ni], 0, 0, 0);
        }

        // all waves' K-loop act reads done before in-place act writes
        __syncthreads();

        // ---------------- epilogue layer l ----------------
        // C/D layout (verified m89/m91): col = lane&15, row = (lane>>4)*4 + reg
        float ws4[4], bs4[4];
        #pragma unroll
        for (int ni = 0; ni < 4; ++ni) {
            int ng = wn8 * 64 + ni * 16 + nlane;
            ws4[ni] = wsum[l * DIM + ng];
            bs4[ni] = bias[l * DIM + ng];
        }

        #pragma unroll
        for (int mi = 0; mi < 2; ++mi)
            #pragma unroll
            for (int r = 0; r < 4; ++r) {
                const int mr = mi * 4 + r;
                const int row = wm * 32 + mi * 16 + q * 4 + r;
                float cc = (l == 0) ? 0.f : sCn[row];
                float vv[4];
                #pragma unroll
                for (int ni = 0; ni < 4; ++ni) {
                    vv[ni] = acc[mi][ni][r] + cc * ws4[ni] + bs4[ni];
                    int colg = wn8 * 64 + ni * 16 + nlane;
                    out[(size_t)(bm + row) * OUTSTRIDE + l * DIM + colg] = vv[ni];
                }
                if (l < 3) {
                    // read x_l at my positions from sAct (before overwrite);
                    // doubles as the capture for vk0 (l=0) / vk1 (l=1)
                    ushort_t xl[4];
                    #pragma unroll
                    for (int ni = 0; ni < 4; ++ni) {
                        int cg = wn8 * 8 + ni * 2 + (nlane >> 3);
                        int kc = cg ^ (row & 15);
                        xl[ni] = sAct[row * DIM + kc * 8 + (nlane & 7)];
                    }
                    float vs = 0.f, dc = 0.f;
                    #pragma unroll
                    for (int ni = 0; ni < 4; ++ni) {
                        vs += vv[ni];
                        dc += vv[ni] * bf16_bits_to_f32(xl[ni]);
                    }
                    float d0 = 0.f, d1 = 0.f, d2 = 0.f;
                    if (l == 0) {
                        d0 = dc;
                        #pragma unroll
                        for (int nip = 0; nip < 2; ++nip)
                            vk0[mr * 2 + nip] =
                                (uint32_t)xl[2 * nip] | ((uint32_t)xl[2 * nip + 1] << 16);
                    } else {
                        #pragma unroll
                        for (int nip = 0; nip < 2; ++nip) {
                            uint32_t p = vk0[mr * 2 + nip];
                            d0 += vv[2 * nip] * bf16_lo(p) + vv[2 * nip + 1] * bf16_hi(p);
                        }
                        if (l == 1) {
                            d1 = dc;
                            #pragma unroll
                            for (int nip = 0; nip < 2; ++nip)
                                vk1[mr * 2 + nip] =
                                    (uint32_t)xl[2 * nip] | ((uint32_t)xl[2 * nip + 1] << 16);
                        } else {   // l == 2
                            #pragma unroll
                            for (int nip = 0; nip < 2; ++nip) {
                                uint32_t p = vk1[mr * 2 + nip];
                                d1 += vv[2 * nip] * bf16_lo(p) + vv[2 * nip + 1] * bf16_hi(p);
                            }
                            d2 = dc;
                        }
                    }
                    // in-place act write: x_{l+1}
                    #pragma unroll
                    for (int ni = 0; ni < 4; ++ni) {
                        int cg = wn8 * 8 + ni * 2 + (nlane >> 3);
                        int kc = cg ^ (row & 15);
                        sAct[row * DIM + kc * 8 + (nlane & 7)] = f32_to_bf16(vv[ni]);
                    }
                    // 16-lane reduce
                    #pragma unroll
                    for (int off = 8; off > 0; off >>= 1) {
                        vs += __shfl_xor(vs, off, 64);
                        d0 += __shfl_xor(d0, off, 64);
                        if (l >= 1) d1 += __shfl_xor(d1, off, 64);
                        if (l >= 2) d2 += __shfl_xor(d2, off, 64);
                    }
                    if (nlane == 0) {
                        sRed[0][wn8][row] = vs;
                        sRed[1][wn8][row] = d0;
                        if (l >= 1) sRed[2][wn8][row] = d1;
                        if (l >= 2) sRed[3][wn8][row] = d2;
                    }
                }
            }

        if (l < 3) {
            __syncthreads();
            if (tid < BM) {
                float vs = 0.f, d0 = 0.f;
                #pragma unroll
                for (int g = 0; g < 8; ++g) { vs += sRed[0][g][tid]; d0 += sRed[1][g][tid]; }
                float c = d0;                                   // j=0: c = 0 + d0 + 0*s0
                if (l >= 1) {
                    float d1 = 0.f;
                    #pragma unroll
                    for (int g = 0; g < 8; ++g) d1 += sRed[2][g][tid];
                    c = c + d1 + c * sSums[1][tid];
                }
                if (l >= 2) {
                    float d2 = 0.f;
                    #pragma unroll
                    for (int g = 0; g < 8; ++g) d2 += sRed[3][g][tid];
                    c = c + d2 + c * sSums[2][tid];
                }
                sCn[tid] = c;
                sSums[l + 1][tid] = vs;
            }
            __syncthreads();
        }
    }
}

// ---------------------------------------------------------------------------
extern "C" void kernel_launch(void* const* d_in, const int* in_sizes, int n_in,
                              void* d_out, int out_size, void* d_ws, size_t ws_size,
                              hipStream_t stream) {
    (void)in_sizes; (void)n_in; (void)out_size; (void)ws_size;
    const float* x0   = (const float*)d_in[0];
    const float* W    = (const float*)d_in[1];
    const float* bias = (const float*)d_in[2];
    float* out = (float*)d_out;

    char* ws = (char*)d_ws;
    // workspace: Wb 4*512*512*2 = 2,097,152 @ 0; wsum 4*512*4 = 8,192 @ 2,097,152
    ushort_t* Wb   = (ushort_t*)ws;
    float*    wsum = (float*)(ws + 2097152);

    prep_kernel<<<NL * DIM, 256, 0, stream>>>(W, Wb, wsum);
    cross_kernel<<<BROWS / BM, 1024, 0, stream>>>(x0, Wb, bias, wsum, out);
}